// Round 16
// baseline (66.910 us; speedup 1.0000x reference)
//
#include <hip/hip_runtime.h>
#include <hip/hip_bf16.h>
#include <stdint.h>

#define HEIGHT 32
#define WIDTH  8192
#define KDIM   256
#define NDIM   512
#define NSLICES 65536                       // B * S = 64 * 1024
#define NMTILES 2048                        // 32 slices per mtile
#define WT_BYTES (NDIM * KDIM * 2)          // 256 KB
#define FEATS_BYTES ((size_t)NSLICES * KDIM * 2)  // 33.5 MB

typedef float f32x4  __attribute__((ext_vector_type(4)));
typedef float f32x16 __attribute__((ext_vector_type(16)));
typedef short bf16x8 __attribute__((ext_vector_type(8)));

__device__ __forceinline__ ushort f2bf(float x) {
  union { float f; uint32_t u; } un; un.f = x;
  uint32_t u = un.u;
  u += 0x7FFFu + ((u >> 16) & 1u);   // round-to-nearest-even
  return (ushort)(u >> 16);
}

__device__ __forceinline__ void load_row8(float* r, const float* p) {
  f32x4 lo = *reinterpret_cast<const f32x4*>(p);
  f32x4 hi = *reinterpret_cast<const f32x4*>(p + 4);
#pragma unroll
  for (int w = 0; w < 4; ++w) { r[w] = lo[w]; r[4 + w] = hi[w]; }
}

// ---- wt2: B-fragment-tiled layout (proven R7-R15) ----
// wt2[((nb*16 + k0)*64 + lane)*8 + e] = bf16(lin_w[k][n]),
//   n = nb*32 + (lane&31), k = k0*16 + (lane>>5)*8 + e.
__global__ __launch_bounds__(256) void prep_wt2_kernel(const float* __restrict__ lin_w,
                                                       ushort* __restrict__ wt2) {
  const int idx = blockIdx.x * 256 + threadIdx.x;   // 0..16383
  const int ln  = idx & 63;
  const int k0  = (idx >> 6) & 15;
  const int nb  = idx >> 10;
  const int n   = nb * 32 + (ln & 31);
  const int kb  = k0 * 16 + (ln >> 5) * 8;
  bf16x8 p;
#pragma unroll
  for (int e = 0; e < 8; ++e) p[e] = (short)f2bf(lin_w[(size_t)(kb + e) * NDIM + n]);
  *reinterpret_cast<bf16x8*>(wt2 + (size_t)idx * 8) = p;
}

// ---------------- kernel 1: streaming conv -> A-fragment-tiled feats2 ----------------
// Block = 1 mtile (32 slices); thread = (slice, 4-row group), rolling 3-row window.
// feats2[((mt*16 + k0)*64 + ln)*8 + e], ln = ((h&1)<<5)|sl, k0 = h>>1, e = w.
__global__ __launch_bounds__(256) void conv_kernel(
    const float* __restrict__ images, const float* __restrict__ conv_w,
    const float* __restrict__ conv_b, ushort* __restrict__ feats2) {
  const int blk = blockIdx.x;
  const int tid = threadIdx.x;

  float cw[9];
#pragma unroll
  for (int i = 0; i < 9; ++i) cw[i] = conv_w[i];
  const float cb = conv_b[0];

  const int sl = tid & 31;            // slice within mtile
  const int q  = tid >> 5;            // 0..7: rows q*4 .. q*4+3
  const int s  = blk * 32 + sl;       // global slice
  const int b  = s >> 10;             // batch (1024 slices per batch)
  const int slb = s & 1023;
  const float* base = images + (size_t)b * (HEIGHT * WIDTH) + (size_t)slb * 8;
  const int h0 = q * 4;

  float pr[8], cu[8], nx[8];
  if (h0 > 0) load_row8(pr, base + (size_t)(h0 - 1) * WIDTH);
  else {
#pragma unroll
    for (int w = 0; w < 8; ++w) pr[w] = 0.f;
  }
  load_row8(cu, base + (size_t)h0 * WIDTH);

#pragma unroll
  for (int i = 0; i < 4; ++i) {
    const int h = h0 + i;
    if (h + 1 < HEIGHT) load_row8(nx, base + (size_t)(h + 1) * WIDTH);
    else {
#pragma unroll
      for (int w = 0; w < 8; ++w) nx[w] = 0.f;
    }
    float y[8];
#pragma unroll
    for (int w = 0; w < 8; ++w) y[w] = cb;
#pragma unroll
    for (int dw = 0; dw < 3; ++dw) {
      const float c0 = cw[dw], c1 = cw[3 + dw], c2 = cw[6 + dw];
#pragma unroll
      for (int w = 0; w < 8; ++w) {
        const int iw = w + dw - 1;            // per-slice zero padding in w
        if (iw >= 0 && iw < 8) {
          y[w] = fmaf(pr[iw], c0, y[w]);
          y[w] = fmaf(cu[iw], c1, y[w]);
          y[w] = fmaf(nx[iw], c2, y[w]);
        }
      }
    }
    bf16x8 pack;
#pragma unroll
    for (int w = 0; w < 8; ++w) pack[w] = (short)f2bf(fmaxf(y[w], 0.f));
    const int ln = ((h & 1) << 5) | sl;
    const int k0 = h >> 1;
    *reinterpret_cast<bf16x8*>(feats2 + (((size_t)blk * 16 + k0) * 64 + ln) * 8) = pack;
#pragma unroll
    for (int w = 0; w < 8; ++w) { pr[w] = cu[w]; cu[w] = nx[w]; }
  }
}

// ---------------- kernel 2: B-register-resident streaming GEMM ----------------
// 512 blocks x 512 threads (8 waves). Block b: mtile range (b&255)*8..+8;
// wave wv handles n-block nb = (b>>8)*8 + wv (32 cols, all K in 64 VGPRs).
// All 8 waves read identical A addresses (L1 broadcast). No LDS, no barriers:
// body = pure stream of {16 A-loads -> 16 MFMA -> 16 stores} per mtile.
__global__ __launch_bounds__(512) void gemm2_kernel(
    const ushort* __restrict__ feats2, const ushort* __restrict__ wt2,
    const float* __restrict__ lin_b, float* __restrict__ out) {
  const int tid  = threadIdx.x;
  const int lane = tid & 63;
  const int wv   = tid >> 6;           // 0..7
  const int blk  = blockIdx.x;         // 0..511
  const int m0   = (blk & 255) * 8;    // first mtile
  const int nb   = ((blk >> 8) << 3) | wv;   // 0..15
  const int la   = lane & 31;
  const int lb   = lane >> 5;

  // B for this nb: 16 frags = 64 VGPRs, loaded once (L2-hot, 1 KB coalesced each)
  bf16x8 Bf[16];
  {
    const ushort* bb = wt2 + ((size_t)nb * 16) * 512 + (size_t)lane * 8;
#pragma unroll
    for (int k0 = 0; k0 < 16; ++k0)
      Bf[k0] = *reinterpret_cast<const bf16x8*>(bb + (size_t)k0 * 512);
  }

  const int col = nb * 32 + la;
  const float bias = lin_b[col];

  for (int mi = 0; mi < 8; ++mi) {
    const int m = m0 + mi;
    const ushort* ab = feats2 + ((size_t)m * 16) * 512 + (size_t)lane * 8;

    f32x16 acc;
#pragma unroll
    for (int i = 0; i < 16; ++i) acc[i] = bias;   // bias via C-init (free)

#pragma unroll
    for (int k0 = 0; k0 < 16; ++k0) {
      const bf16x8 af = *reinterpret_cast<const bf16x8*>(ab + (size_t)k0 * 512);
      acc = __builtin_amdgcn_mfma_f32_32x32x16_bf16(af, Bf[k0], acc, 0, 0, 0);
    }

    const size_t row0 = (size_t)m * 32;
#pragma unroll
    for (int reg = 0; reg < 16; ++reg) {
      const int rr = (reg & 3) + 8 * (reg >> 2) + 4 * lb;
      out[(row0 + rr) * NDIM + col] = acc[reg];
    }
  }
}

// ---------------- fallback (ws too small): R13 fused kernel ----------------
__global__ __launch_bounds__(256) void fused_kernel(
    const float* __restrict__ images, const float* __restrict__ conv_w,
    const float* __restrict__ conv_b, const ushort* __restrict__ wt2,
    const float* __restrict__ lin_b, float* __restrict__ out) {
  __shared__ ushort A[16 * 64 * 8];
  const int tid = threadIdx.x;
  const int blk = blockIdx.x;

  float cw[9];
#pragma unroll
  for (int i = 0; i < 9; ++i) cw[i] = conv_w[i];
  const float cb = conv_b[0];

  {
    const int sl = tid & 31;
    const int q  = tid >> 5;
    const int s  = blk * 32 + sl;
    const int b  = s >> 10;
    const int slb = s & 1023;
    const float* base = images + (size_t)b * (HEIGHT * WIDTH) + (size_t)slb * 8;
    const int h0 = q * 4;

    float pr[8], cu[8], nx[8];
    if (h0 > 0) load_row8(pr, base + (size_t)(h0 - 1) * WIDTH);
    else {
#pragma unroll
      for (int w = 0; w < 8; ++w) pr[w] = 0.f;
    }
    load_row8(cu, base + (size_t)h0 * WIDTH);

#pragma unroll
    for (int i = 0; i < 4; ++i) {
      const int h = h0 + i;
      if (h + 1 < HEIGHT) load_row8(nx, base + (size_t)(h + 1) * WIDTH);
      else {
#pragma unroll
        for (int w = 0; w < 8; ++w) nx[w] = 0.f;
      }
      float y[8];
#pragma unroll
      for (int w = 0; w < 8; ++w) y[w] = cb;
#pragma unroll
      for (int dw = 0; dw < 3; ++dw) {
        const float c0 = cw[dw], c1 = cw[3 + dw], c2 = cw[6 + dw];
#pragma unroll
        for (int w = 0; w < 8; ++w) {
          const int iw = w + dw - 1;
          if (iw >= 0 && iw < 8) {
            y[w] = fmaf(pr[iw], c0, y[w]);
            y[w] = fmaf(cu[iw], c1, y[w]);
            y[w] = fmaf(nx[iw], c2, y[w]);
          }
        }
      }
      bf16x8 pack;
#pragma unroll
      for (int w = 0; w < 8; ++w) pack[w] = (short)f2bf(fmaxf(y[w], 0.f));
      const int ln = ((h & 1) << 5) | sl;
      const int k0 = h >> 1;
      *reinterpret_cast<bf16x8*>(A + ((size_t)k0 * 64 + ln) * 8) = pack;
#pragma unroll
      for (int w = 0; w < 8; ++w) { pr[w] = cu[w]; cu[w] = nx[w]; }
    }
  }
  __syncthreads();

  const int lane = tid & 63;
  const int wv   = tid >> 6;
  const int la   = lane & 31;
  const int lb   = lane >> 5;
  const size_t row0 = (size_t)blk * 32;
  const ushort* abase = A + (size_t)lane * 8;

#pragma unroll
  for (int pass = 0; pass < 2; ++pass) {
    const int nfb = wv * 4 + pass * 2;
    const ushort* bb = wt2 + ((size_t)nfb * 16) * 512 + (size_t)lane * 8;

    f32x16 acc0, acc1;
#pragma unroll
    for (int i = 0; i < 16; ++i) { acc0[i] = 0.f; acc1[i] = 0.f; }

#pragma unroll
    for (int k0 = 0; k0 < 16; ++k0) {
      const bf16x8 af  = *reinterpret_cast<const bf16x8*>(abase + (size_t)k0 * 512);
      const bf16x8 bf0 = *reinterpret_cast<const bf16x8*>(bb + (size_t)k0 * 512);
      const bf16x8 bf1 = *reinterpret_cast<const bf16x8*>(bb + (size_t)(16 + k0) * 512);
      acc0 = __builtin_amdgcn_mfma_f32_32x32x16_bf16(af, bf0, acc0, 0, 0, 0);
      acc1 = __builtin_amdgcn_mfma_f32_32x32x16_bf16(af, bf1, acc1, 0, 0, 0);
    }

#pragma unroll
    for (int nf = 0; nf < 2; ++nf) {
      const int col = (nfb + nf) * 32 + la;
      const float bias = lin_b[col];
      const f32x16& a = nf ? acc1 : acc0;
#pragma unroll
      for (int reg = 0; reg < 16; ++reg) {
        const int rr = (reg & 3) + 8 * (reg >> 2) + 4 * lb;
        out[(row0 + rr) * NDIM + col] = a[reg] + bias;
      }
    }
  }
}

extern "C" void kernel_launch(void* const* d_in, const int* in_sizes, int n_in,
                              void* d_out, int out_size, void* d_ws, size_t ws_size,
                              hipStream_t stream) {
  const float* images = (const float*)d_in[0];
  const float* conv_w = (const float*)d_in[1];
  const float* conv_b = (const float*)d_in[2];
  const float* lin_w  = (const float*)d_in[3];
  const float* lin_b  = (const float*)d_in[4];
  float* out = (float*)d_out;
  ushort* wt2 = (ushort*)d_ws;      // 256 KB

  hipLaunchKernelGGL(prep_wt2_kernel, dim3(64), dim3(256), 0, stream, lin_w, wt2);

  if (ws_size >= (size_t)WT_BYTES + FEATS_BYTES) {
    ushort* feats2 = (ushort*)((char*)d_ws + WT_BYTES);
    hipLaunchKernelGGL(conv_kernel, dim3(NMTILES), dim3(256), 0, stream,
                       images, conv_w, conv_b, feats2);
    hipLaunchKernelGGL(gemm2_kernel, dim3(512), dim3(512), 0, stream,
                       feats2, wt2, lin_b, out);
  } else {
    hipLaunchKernelGGL(fused_kernel, dim3(NMTILES), dim3(256), 0, stream,
                       images, conv_w, conv_b, wt2, lin_b, out);
  }
}